// Round 1
// baseline (413.329 us; speedup 1.0000x reference)
//
#include <hip/hip_runtime.h>
#include <hip/hip_bf16.h>
#include <cmath>

#define N_NODES 50000
#define N_EDGES 800000
#define IN_F 256
#define HEADS 8
#define DHEAD 32
#define NOUT 256  // HEADS*DHEAD

// ---------------- GEMM: h[n, 256] = x[n, 256] @ Wf[256, 256] ----------------
// Wf[i][c] = W[c/32][i][c%32].  fp32 vector FMA (no fp32 MFMA on CDNA4).
__global__ __launch_bounds__(256) void proj_gemm(const float* __restrict__ x,
                                                 const float* __restrict__ W,
                                                 float* __restrict__ h) {
  __shared__ float xs[16][68];   // [k][m], row stride 272B (16B aligned)
  __shared__ float ws2[16][68];  // [k][n]
  const int bm = blockIdx.x * 64;
  const int bn = blockIdx.y * 64;
  const int tid = threadIdx.x;
  const int xr = tid >> 2;         // 0..63 row in tile
  const int xk = (tid & 3) << 2;   // 0,4,8,12
  const int wk = tid >> 4;         // 0..15
  const int wn = (tid & 15) << 2;  // 0..60
  const int tm = (tid >> 4) << 2;
  const int tn = (tid & 15) << 2;
  float acc[4][4] = {};
  for (int k0 = 0; k0 < IN_F; k0 += 16) {
    int row = bm + xr;
    row = row < N_NODES ? row : N_NODES - 1;  // clamp; stores are guarded
    const float4 xv = *(const float4*)&x[row * IN_F + k0 + xk];
    xs[xk + 0][xr] = xv.x;
    xs[xk + 1][xr] = xv.y;
    xs[xk + 2][xr] = xv.z;
    xs[xk + 3][xr] = xv.w;
    const int col = bn + wn;  // wn%4==0 so the 4 cols stay inside one head
    const int head = col >> 5, dd = col & 31;
    const float4 wv =
        *(const float4*)&W[head * (IN_F * DHEAD) + (k0 + wk) * DHEAD + dd];
    *(float4*)&ws2[wk][wn] = wv;
    __syncthreads();
#pragma unroll
    for (int k = 0; k < 16; ++k) {
      const float4 av = *(const float4*)&xs[k][tm];
      const float4 bv = *(const float4*)&ws2[k][tn];
      const float aa[4] = {av.x, av.y, av.z, av.w};
      const float bb[4] = {bv.x, bv.y, bv.z, bv.w};
#pragma unroll
      for (int i = 0; i < 4; ++i)
#pragma unroll
        for (int j = 0; j < 4; ++j) acc[i][j] += aa[i] * bb[j];
    }
    __syncthreads();
  }
#pragma unroll
  for (int i = 0; i < 4; ++i) {
    const int row = bm + tm + i;
    if (row < N_NODES) {
      float4 o = make_float4(acc[i][0], acc[i][1], acc[i][2], acc[i][3]);
      *(float4*)&h[row * NOUT + bn + tn] = o;
    }
  }
}

// ---------------- CSR build: histogram -> scan -> scatter ----------------
__global__ void hist_kernel(const int* __restrict__ src, int* __restrict__ count) {
  const int i = blockIdx.x * blockDim.x + threadIdx.x;
  if (i < N_EDGES) atomicAdd(&count[src[i]], 1);
}

__global__ __launch_bounds__(1024) void scan_kernel(const int* __restrict__ count,
                                                    int* __restrict__ row_start,
                                                    int* __restrict__ cursor,
                                                    int n) {
  __shared__ int buf[1024];
  const int t = threadIdx.x;
  const int chunk = (n + 1023) >> 10;  // 49
  const int b0 = t * chunk;
  const int b1 = min(b0 + chunk, n);
  int sum = 0;
  for (int i = b0; i < b1; ++i) sum += count[i];
  buf[t] = sum;
  int val = sum;
  for (int off = 1; off < 1024; off <<= 1) {
    __syncthreads();
    const int tmp = (t >= off) ? buf[t - off] : 0;
    __syncthreads();
    val += tmp;
    buf[t] = val;
  }
  __syncthreads();
  int off = val - sum;  // exclusive prefix for this chunk
  for (int i = b0; i < b1; ++i) {
    row_start[i] = off;
    cursor[i] = off;
    off += count[i];
  }
  if (t == 1023) row_start[n] = val;  // total = N_EDGES
}

__global__ void scatter_kernel(const int* __restrict__ src,
                               const int* __restrict__ dst,
                               int* __restrict__ cursor,
                               int* __restrict__ csr_dst) {
  const int i = blockIdx.x * blockDim.x + threadIdx.x;
  if (i < N_EDGES) {
    const int s = src[i];
    const int pos = atomicAdd(&cursor[s], 1);
    csr_dst[pos] = dst[i];
  }
}

// ---------------- fused edge pass: one wave per src node ----------------
// lin[e,h] = c_node[h] + dot(hd, b_node[h]) + dot(|hd-hs|, a4[h])
//   b_node = a2 + a3 + hs*a5 ;  c_node = dot(hs, a1) - dot(hs, a3)
// online softmax (running max m, sum s) -> single gather of h[dst] per edge.
__global__ __launch_bounds__(256) void gat_edge(const float* __restrict__ h,
                                                const float* __restrict__ a,
                                                const int* __restrict__ row_start,
                                                const int* __restrict__ csr_dst,
                                                float* __restrict__ out) {
  const int wave = threadIdx.x >> 6;
  const int lane = threadIdx.x & 63;
  const int node = blockIdx.x * 4 + wave;
  if (node >= N_NODES) return;
  const int c = lane << 2;  // 4 channels per lane; head = c/32
  const int head = c >> 5;
  const int dd = c & 31;
  const float* ah = a + head * 160 + dd;
  const float4 a1 = *(const float4*)(ah);
  const float4 a2 = *(const float4*)(ah + 32);
  const float4 a3 = *(const float4*)(ah + 64);
  const float4 a4v = *(const float4*)(ah + 96);
  const float4 a5 = *(const float4*)(ah + 128);
  const float4 hs = *(const float4*)&h[node * NOUT + c];
  float4 b;
  b.x = a2.x + a3.x + hs.x * a5.x;
  b.y = a2.y + a3.y + hs.y * a5.y;
  b.z = a2.z + a3.z + hs.z * a5.z;
  b.w = a2.w + a3.w + hs.w * a5.w;
  float cn = hs.x * (a1.x - a3.x) + hs.y * (a1.y - a3.y) +
             hs.z * (a1.z - a3.z) + hs.w * (a1.w - a3.w);
  cn += __shfl_xor(cn, 1);
  cn += __shfl_xor(cn, 2);
  cn += __shfl_xor(cn, 4);  // per-head constant, uniform in 8-lane group

  float m = -INFINITY, s = 0.f;
  float4 acc = make_float4(0.f, 0.f, 0.f, 0.f);
  int e = row_start[node];
  const int e_end = row_start[node + 1];
  float4 hd_pre = make_float4(0.f, 0.f, 0.f, 0.f);
  if (e < e_end) {
    const int j = csr_dst[e];
    hd_pre = *(const float4*)&h[j * NOUT + c];
  }
  for (; e < e_end; ++e) {
    const float4 hd = hd_pre;
    if (e + 1 < e_end) {  // prefetch next gather under this edge's compute
      const int j2 = csr_dst[e + 1];
      hd_pre = *(const float4*)&h[j2 * NOUT + c];
    }
    float p = hd.x * b.x + fabsf(hd.x - hs.x) * a4v.x;
    p += hd.y * b.y + fabsf(hd.y - hs.y) * a4v.y;
    p += hd.z * b.z + fabsf(hd.z - hs.z) * a4v.z;
    p += hd.w * b.w + fabsf(hd.w - hs.w) * a4v.w;
    p += __shfl_xor(p, 1);
    p += __shfl_xor(p, 2);
    p += __shfl_xor(p, 4);
    const float lin = cn + p;
    const float alpha = lin > 0.f ? lin : 0.2f * lin;
    const float mn = fmaxf(m, alpha);
    const float r = __expf(m - mn);   // m=-inf first edge -> r=0
    const float w = __expf(alpha - mn);
    s = s * r + w;
    acc.x = acc.x * r + w * hd.x;
    acc.y = acc.y * r + w * hd.y;
    acc.z = acc.z * r + w * hd.z;
    acc.w = acc.w * r + w * hd.w;
    m = mn;
  }
  const float inv = 1.0f / (s + 1e-16f);
  float4 o = make_float4(acc.x * inv, acc.y * inv, acc.z * inv, acc.w * inv);
  *(float4*)&out[node * NOUT + c] = o;
}

extern "C" void kernel_launch(void* const* d_in, const int* in_sizes, int n_in,
                              void* d_out, int out_size, void* d_ws, size_t ws_size,
                              hipStream_t stream) {
  const float* x = (const float*)d_in[0];
  const float* W = (const float*)d_in[1];
  const float* a = (const float*)d_in[2];
  const int* src = (const int*)d_in[3];
  const int* dst = (const int*)d_in[4];
  float* out = (float*)d_out;

  char* ws = (char*)d_ws;
  float* h = (float*)ws;  // 50000*256*4 = 51.2 MB
  size_t off = (size_t)N_NODES * NOUT * sizeof(float);
  int* count = (int*)(ws + off);     off += 50048 * sizeof(int);
  int* row_start = (int*)(ws + off); off += 50048 * sizeof(int);
  int* cursor = (int*)(ws + off);    off += 50048 * sizeof(int);
  int* csr_dst = (int*)(ws + off);   off += (size_t)N_EDGES * sizeof(int);
  // total ~54.8 MB of workspace

  hipMemsetAsync(count, 0, N_NODES * sizeof(int), stream);

  dim3 gemm_grid((N_NODES + 63) / 64, 4);
  proj_gemm<<<gemm_grid, 256, 0, stream>>>(x, W, h);

  hist_kernel<<<(N_EDGES + 255) / 256, 256, 0, stream>>>(src, count);
  scan_kernel<<<1, 1024, 0, stream>>>(count, row_start, cursor, N_NODES);
  scatter_kernel<<<(N_EDGES + 255) / 256, 256, 0, stream>>>(src, dst, cursor, csr_dst);

  gat_edge<<<(N_NODES + 3) / 4, 256, 0, stream>>>(h, a, row_start, csr_dst, out);
}

// Round 2
// 308.578 us; speedup vs baseline: 1.3395x; 1.3395x over previous
//
#include <hip/hip_runtime.h>
#include <hip/hip_bf16.h>
#include <cmath>

#define N_NODES 50000
#define N_EDGES 800000
#define IN_F 256
#define NOUT 256

typedef __bf16 bf16x8 __attribute__((ext_vector_type(8)));
typedef float f32x4 __attribute__((ext_vector_type(4)));

__device__ __forceinline__ ushort f2bf(float f) {
  union { float f; unsigned u; } v; v.f = f;
  unsigned r = v.u + 0x7fffu + ((v.u >> 16) & 1u);
  return (ushort)(r >> 16);
}

__device__ __forceinline__ void unpack8(uint4 v, float* o) {
  union { unsigned u; float f; } t;
  unsigned uu[4] = {v.x, v.y, v.z, v.w};
#pragma unroll
  for (int q = 0; q < 4; ++q) {
    t.u = uu[q] << 16;         o[2 * q] = t.f;
    t.u = uu[q] & 0xffff0000u; o[2 * q + 1] = t.f;
  }
}

// ---- x fp32 -> bf16 (xb lives in d_out's tail-unused space) ----
__global__ __launch_bounds__(256) void convert_x(const float* __restrict__ x,
                                                 ushort* __restrict__ xb) {
  const size_t i = (size_t)blockIdx.x * 256 + threadIdx.x;  // one float4 each
  const float4 v = *(const float4*)&x[i * 4];
  ushort4 o;
  o.x = f2bf(v.x); o.y = f2bf(v.y); o.z = f2bf(v.z); o.w = f2bf(v.w);
  *(ushort4*)&xb[i * 4] = o;
}

// ---- WT[c][k] = bf16(W[c/32][k][c%32]), c=head*32+d ----
__global__ __launch_bounds__(256) void convert_w(const float* __restrict__ W,
                                                 ushort* __restrict__ WT) {
  const int c = blockIdx.x, k = threadIdx.x;
  WT[c * 256 + k] = f2bf(W[((c >> 5) * 256 + k) * 32 + (c & 31)]);
}

// ---- h[node][ch] = sum_k x[node][k] * WT[ch][k], bf16 MFMA ----
// A-op = WT channel-tile (M=channels), B-op = x node-tile (N=nodes):
// D col(lane&15)=node, D row((lane>>4)*4+reg)=channel -> 4 consecutive
// channels per lane -> packed 8B bf16 store.
__global__ __launch_bounds__(256) void proj_gemm(const ushort* __restrict__ xb,
                                                 const ushort* __restrict__ WT,
                                                 ushort* __restrict__ hb) {
  __shared__ ushort Xl[8][128][8];  // [kc][node][8k] 16KB
  __shared__ ushort Wl[8][128][8];  // [kc][chan][8k] 16KB
  const int bm = blockIdx.x * 128;   // node base
  const int bch = blockIdx.y * 128;  // channel base
  const int tid = threadIdx.x;
  const int w = tid >> 6, lane = tid & 63;
  const int wch = w >> 1, wnd = w & 1;
  const int l15 = lane & 15, l4 = lane >> 4;
  f32x4 acc[4][4] = {};
  for (int ks = 0; ks < 4; ++ks) {
    const int k0 = ks * 64;
    __syncthreads();  // previous compute done before overwrite
    for (int it = w; it < 32; it += 4) {
      const int kc = (it & 15) >> 1, half = it & 1;
      if (it < 16) {
        int row = bm + half * 64 + lane;
        row = row < N_NODES ? row : N_NODES - 1;
        const ushort* gp = xb + (size_t)row * 256 + k0 + kc * 8;
        __builtin_amdgcn_global_load_lds(
            (const __attribute__((address_space(1))) void*)gp,
            (__attribute__((address_space(3))) void*)&Xl[kc][half * 64][0],
            16, 0, 0);
      } else {
        const int crow = bch + half * 64 + lane;
        const ushort* gp = WT + (size_t)crow * 256 + k0 + kc * 8;
        __builtin_amdgcn_global_load_lds(
            (const __attribute__((address_space(1))) void*)gp,
            (__attribute__((address_space(3))) void*)&Wl[kc][half * 64][0],
            16, 0, 0);
      }
    }
    __syncthreads();
#pragma unroll
    for (int t = 0; t < 2; ++t) {
      const int kc = t * 4 + l4;
      bf16x8 bfr[4];
#pragma unroll
      for (int j = 0; j < 4; ++j)
        bfr[j] = *(const bf16x8*)&Xl[kc][wnd * 64 + j * 16 + l15][0];
#pragma unroll
      for (int i = 0; i < 4; ++i) {
        const bf16x8 af = *(const bf16x8*)&Wl[kc][wch * 64 + i * 16 + l15][0];
#pragma unroll
        for (int j = 0; j < 4; ++j)
          acc[i][j] = __builtin_amdgcn_mfma_f32_16x16x32_bf16(af, bfr[j],
                                                              acc[i][j], 0, 0, 0);
      }
    }
  }
#pragma unroll
  for (int i = 0; i < 4; ++i) {
#pragma unroll
    for (int j = 0; j < 4; ++j) {
      const int node = bm + wnd * 64 + j * 16 + l15;
      if (node < N_NODES) {
        const int ch = bch + wch * 64 + i * 16 + l4 * 4;
        ushort4 o;
        o.x = f2bf(acc[i][j][0]); o.y = f2bf(acc[i][j][1]);
        o.z = f2bf(acc[i][j][2]); o.w = f2bf(acc[i][j][3]);
        *(ushort4*)&hb[(size_t)node * 256 + ch] = o;
      }
    }
  }
}

// ---------------- CSR build ----------------
__global__ void hist_kernel(const int* __restrict__ src, int* __restrict__ count) {
  const int i = blockIdx.x * blockDim.x + threadIdx.x;
  if (i < N_EDGES) atomicAdd(&count[src[i]], 1);
}

__global__ __launch_bounds__(1024) void scan_kernel(const int* __restrict__ count,
                                                    int* __restrict__ row_start,
                                                    int* __restrict__ cursor,
                                                    int n) {
  __shared__ int buf[1024];
  const int t = threadIdx.x;
  const int chunk = (n + 1023) >> 10;
  const int b0 = t * chunk;
  const int b1 = min(b0 + chunk, n);
  int sum = 0;
  for (int i = b0; i < b1; ++i) sum += count[i];
  buf[t] = sum;
  int val = sum;
  for (int off = 1; off < 1024; off <<= 1) {
    __syncthreads();
    const int tmp = (t >= off) ? buf[t - off] : 0;
    __syncthreads();
    val += tmp;
    buf[t] = val;
  }
  __syncthreads();
  int off = val - sum;
  for (int i = b0; i < b1; ++i) {
    row_start[i] = off;
    cursor[i] = off;
    off += count[i];
  }
  if (t == 1023) row_start[n] = val;
}

__global__ void scatter_kernel(const int* __restrict__ src,
                               const int* __restrict__ dst,
                               int* __restrict__ cursor,
                               int* __restrict__ csr_dst) {
  const int i = blockIdx.x * blockDim.x + threadIdx.x;
  if (i < N_EDGES) {
    const int s = src[i];
    const int pos = atomicAdd(&cursor[s], 1);
    csr_dst[pos] = dst[i];
  }
}

// ---------------- fused edge pass: one wave per src node, 2 edges/iter ----
// lanes 0-31 handle even edges, 32-63 odd edges; each lane: 8 channels (16B
// bf16 gather). 4-lane shfl reduce per head; online softmax; merge halves.
__global__ __launch_bounds__(256) void gat_edge(const ushort* __restrict__ hb,
                                                const float* __restrict__ a,
                                                const int* __restrict__ row_start,
                                                const int* __restrict__ csr_dst,
                                                float* __restrict__ out) {
  const int wv = threadIdx.x >> 6;
  const int lane = threadIdx.x & 63;
  const int node = blockIdx.x * 4 + wv;
  if (node >= N_NODES) return;
  const int eoff = lane >> 5;
  const int l32 = lane & 31;
  const int head = l32 >> 2;
  const int c0 = l32 * 8;  // 8 consecutive channels per lane
  const float* ah = a + head * 160 + ((l32 & 3) * 8);

  float a1[8], a2[8], a3[8], a4v[8], a5[8];
  *(float4*)&a1[0] = *(const float4*)(ah + 0);   *(float4*)&a1[4] = *(const float4*)(ah + 4);
  *(float4*)&a2[0] = *(const float4*)(ah + 32);  *(float4*)&a2[4] = *(const float4*)(ah + 36);
  *(float4*)&a3[0] = *(const float4*)(ah + 64);  *(float4*)&a3[4] = *(const float4*)(ah + 68);
  *(float4*)&a4v[0] = *(const float4*)(ah + 96); *(float4*)&a4v[4] = *(const float4*)(ah + 100);
  *(float4*)&a5[0] = *(const float4*)(ah + 128); *(float4*)&a5[4] = *(const float4*)(ah + 132);

  float hs[8];
  unpack8(*(const uint4*)&hb[(size_t)node * 256 + c0], hs);
  float b[8];
  float cn = 0.f;
#pragma unroll
  for (int q = 0; q < 8; ++q) {
    b[q] = a2[q] + a3[q] + hs[q] * a5[q];
    cn += hs[q] * (a1[q] - a3[q]);
  }
  cn += __shfl_xor(cn, 1);
  cn += __shfl_xor(cn, 2);

  float m = -INFINITY, s = 0.f;
  float acc[8] = {0.f, 0.f, 0.f, 0.f, 0.f, 0.f, 0.f, 0.f};
  const int e0 = row_start[node], e1 = row_start[node + 1];
  const int cnt = e1 - e0;
  if (cnt > 0) {
    const int nit = (cnt + 1) >> 1;
    int idx = e0 + eoff;
    bool val = eoff < cnt;
    int j = csr_dst[val ? idx : e0];
    uint4 hv = *(const uint4*)&hb[(size_t)j * 256 + c0];
    for (int it = 0; it < nit; ++it) {
      const bool cv = val;
      const uint4 cur = hv;
      idx += 2;
      val = idx < e1;
      if (val) {  // prefetch next pair's gather under this pair's compute
        j = csr_dst[idx];
        hv = *(const uint4*)&hb[(size_t)j * 256 + c0];
      }
      float hd[8];
      unpack8(cur, hd);
      float p = 0.f;
#pragma unroll
      for (int q = 0; q < 8; ++q)
        p += hd[q] * b[q] + fabsf(hd[q] - hs[q]) * a4v[q];
      p += __shfl_xor(p, 1);
      p += __shfl_xor(p, 2);
      if (cv) {
        const float lin = cn + p;
        const float alpha = lin > 0.f ? lin : 0.2f * lin;
        const float mn = fmaxf(m, alpha);
        const float r = __expf(m - mn);  // m=-inf first edge -> 0
        const float wgt = __expf(alpha - mn);
        s = s * r + wgt;
#pragma unroll
        for (int q = 0; q < 8; ++q) acc[q] = acc[q] * r + wgt * hd[q];
        m = mn;
      }
    }
  }
  // merge the two half-wave softmax streams
  const float mo = __shfl_xor(m, 32);
  const float so = __shfl_xor(s, 32);
  const float mn = fmaxf(m, mo);
  const float r1 = (m > -INFINITY) ? __expf(m - mn) : 0.f;
  const float r2 = (mo > -INFINITY) ? __expf(mo - mn) : 0.f;
  const float inv = 1.f / (s * r1 + so * r2 + 1e-16f);
  float o[8];
#pragma unroll
  for (int q = 0; q < 8; ++q) {
    const float ao = __shfl_xor(acc[q], 32);
    o[q] = (acc[q] * r1 + ao * r2) * inv;
  }
  if (eoff == 0) {
    *(float4*)&out[(size_t)node * 256 + c0] = make_float4(o[0], o[1], o[2], o[3]);
    *(float4*)&out[(size_t)node * 256 + c0 + 4] = make_float4(o[4], o[5], o[6], o[7]);
  }
}

extern "C" void kernel_launch(void* const* d_in, const int* in_sizes, int n_in,
                              void* d_out, int out_size, void* d_ws, size_t ws_size,
                              hipStream_t stream) {
  const float* x = (const float*)d_in[0];
  const float* W = (const float*)d_in[1];
  const float* a = (const float*)d_in[2];
  const int* src = (const int*)d_in[3];
  const int* dst = (const int*)d_in[4];
  float* out = (float*)d_out;

  char* ws = (char*)d_ws;
  ushort* hb = (ushort*)ws;                       // 25.6 MB bf16 h
  size_t off = (size_t)N_NODES * 256 * 2;
  ushort* WT = (ushort*)(ws + off); off += 256 * 256 * 2;
  int* count = (int*)(ws + off);     off += 50048 * sizeof(int);
  int* row_start = (int*)(ws + off); off += 50048 * sizeof(int);
  int* cursor = (int*)(ws + off);    off += 50048 * sizeof(int);
  int* csr_dst = (int*)(ws + off);   off += (size_t)N_EDGES * sizeof(int);

  // bf16 x staged in d_out (fully overwritten by gat_edge at the end)
  ushort* xb = (ushort*)d_out;

  hipMemsetAsync(count, 0, N_NODES * sizeof(int), stream);

  convert_x<<<12500, 256, 0, stream>>>(x, xb);  // 12500*256*4 = 12.8M elems
  convert_w<<<256, 256, 0, stream>>>(W, WT);

  hist_kernel<<<(N_EDGES + 255) / 256, 256, 0, stream>>>(src, count);
  scan_kernel<<<1, 1024, 0, stream>>>(count, row_start, cursor, N_NODES);
  scatter_kernel<<<(N_EDGES + 255) / 256, 256, 0, stream>>>(src, dst, cursor, csr_dst);

  dim3 gemm_grid(391, 2);  // 391*128 = 50048 node rows, 2 channel halves
  proj_gemm<<<gemm_grid, 256, 0, stream>>>(xb, WT, hb);

  gat_edge<<<12500, 256, 0, stream>>>(hb, a, row_start, csr_dst, out);
}

// Round 3
// 219.383 us; speedup vs baseline: 1.8841x; 1.4066x over previous
//
#include <hip/hip_runtime.h>
#include <hip/hip_bf16.h>
#include <cmath>

#define N_NODES 50000
#define N_EDGES 800000
#define IN_F 256
#define NOUT 256
#define NB_SCAN 196  // 196*256 = 50176 >= N_NODES

typedef __bf16 bf16x8 __attribute__((ext_vector_type(8)));
typedef float f32x4 __attribute__((ext_vector_type(4)));

__device__ __forceinline__ ushort f2bf(float f) {
  union { float f; unsigned u; } v; v.f = f;
  unsigned r = v.u + 0x7fffu + ((v.u >> 16) & 1u);
  return (ushort)(r >> 16);
}

__device__ __forceinline__ void unpack8(uint4 v, float* o) {
  union { unsigned u; float f; } t;
  unsigned uu[4] = {v.x, v.y, v.z, v.w};
#pragma unroll
  for (int q = 0; q < 4; ++q) {
    t.u = uu[q] << 16;         o[2 * q] = t.f;
    t.u = uu[q] & 0xffff0000u; o[2 * q + 1] = t.f;
  }
}

// ---- x fp32 -> bf16 (xb lives in d_out, overwritten later) ----
__global__ __launch_bounds__(256) void convert_x(const float* __restrict__ x,
                                                 ushort* __restrict__ xb) {
  const size_t i = (size_t)blockIdx.x * 256 + threadIdx.x;
  const float4 v = *(const float4*)&x[i * 4];
  ushort4 o;
  o.x = f2bf(v.x); o.y = f2bf(v.y); o.z = f2bf(v.z); o.w = f2bf(v.w);
  *(ushort4*)&xb[i * 4] = o;
}

// ---- WT[c][k] = bf16(W[c/32][k][c%32]) ----
__global__ __launch_bounds__(256) void convert_w(const float* __restrict__ W,
                                                 ushort* __restrict__ WT) {
  const int c = blockIdx.x, k = threadIdx.x;
  WT[c * 256 + k] = f2bf(W[((c >> 5) * 256 + k) * 32 + (c & 31)]);
}

// ---- h = x @ W per head, bf16 MFMA, packed bf16 output ----
__global__ __launch_bounds__(256) void proj_gemm(const ushort* __restrict__ xb,
                                                 const ushort* __restrict__ WT,
                                                 ushort* __restrict__ hb) {
  __shared__ ushort Xl[8][128][8];
  __shared__ ushort Wl[8][128][8];
  const int bm = blockIdx.x * 128;
  const int bch = blockIdx.y * 128;
  const int tid = threadIdx.x;
  const int w = tid >> 6, lane = tid & 63;
  const int wch = w >> 1, wnd = w & 1;
  const int l15 = lane & 15, l4 = lane >> 4;
  f32x4 acc[4][4] = {};
  for (int ks = 0; ks < 4; ++ks) {
    const int k0 = ks * 64;
    __syncthreads();
    for (int it = w; it < 32; it += 4) {
      const int kc = (it & 15) >> 1, half = it & 1;
      if (it < 16) {
        int row = bm + half * 64 + lane;
        row = row < N_NODES ? row : N_NODES - 1;
        const ushort* gp = xb + (size_t)row * 256 + k0 + kc * 8;
        __builtin_amdgcn_global_load_lds(
            (const __attribute__((address_space(1))) void*)gp,
            (__attribute__((address_space(3))) void*)&Xl[kc][half * 64][0],
            16, 0, 0);
      } else {
        const int crow = bch + half * 64 + lane;
        const ushort* gp = WT + (size_t)crow * 256 + k0 + kc * 8;
        __builtin_amdgcn_global_load_lds(
            (const __attribute__((address_space(1))) void*)gp,
            (__attribute__((address_space(3))) void*)&Wl[kc][half * 64][0],
            16, 0, 0);
      }
    }
    __syncthreads();
#pragma unroll
    for (int t = 0; t < 2; ++t) {
      const int kc = t * 4 + l4;
      bf16x8 bfr[4];
#pragma unroll
      for (int j = 0; j < 4; ++j)
        bfr[j] = *(const bf16x8*)&Xl[kc][wnd * 64 + j * 16 + l15][0];
#pragma unroll
      for (int i = 0; i < 4; ++i) {
        const bf16x8 af = *(const bf16x8*)&Wl[kc][wch * 64 + i * 16 + l15][0];
#pragma unroll
        for (int j = 0; j < 4; ++j)
          acc[i][j] = __builtin_amdgcn_mfma_f32_16x16x32_bf16(af, bfr[j],
                                                              acc[i][j], 0, 0, 0);
      }
    }
  }
#pragma unroll
  for (int i = 0; i < 4; ++i) {
#pragma unroll
    for (int j = 0; j < 4; ++j) {
      const int node = bm + wnd * 64 + j * 16 + l15;
      if (node < N_NODES) {
        const int ch = bch + wch * 64 + i * 16 + l4 * 4;
        ushort4 o;
        o.x = f2bf(acc[i][j][0]); o.y = f2bf(acc[i][j][1]);
        o.z = f2bf(acc[i][j][2]); o.w = f2bf(acc[i][j][3]);
        *(ushort4*)&hb[(size_t)node * 256 + ch] = o;
      }
    }
  }
}

// ---------------- CSR build: hist -> hierarchical scan -> scatter --------
__global__ void hist_kernel(const int* __restrict__ src, int* __restrict__ count) {
  const int i = blockIdx.x * blockDim.x + threadIdx.x;
  if (i < N_EDGES) atomicAdd(&count[src[i]], 1);
}

__global__ __launch_bounds__(256) void block_sum(const int* __restrict__ count,
                                                 int* __restrict__ bsum) {
  const int i = blockIdx.x * 256 + threadIdx.x;
  int v = (i < N_NODES) ? count[i] : 0;
#pragma unroll
  for (int off = 1; off < 64; off <<= 1) v += __shfl_xor(v, off);
  __shared__ int wsum[4];
  if ((threadIdx.x & 63) == 0) wsum[threadIdx.x >> 6] = v;
  __syncthreads();
  if (threadIdx.x == 0) bsum[blockIdx.x] = wsum[0] + wsum[1] + wsum[2] + wsum[3];
}

__global__ __launch_bounds__(256) void scan_bsums(const int* __restrict__ bsum,
                                                  int* __restrict__ boff,
                                                  int* __restrict__ row_start) {
  __shared__ int buf[256];
  const int t = threadIdx.x;
  const int v = (t < NB_SCAN) ? bsum[t] : 0;
  buf[t] = v;
  int val = v;
  for (int off = 1; off < 256; off <<= 1) {
    __syncthreads();
    const int tmp = (t >= off) ? buf[t - off] : 0;
    __syncthreads();
    val += tmp;
    buf[t] = val;
  }
  if (t < NB_SCAN) boff[t] = val - v;  // exclusive block offset
  if (t == 255) row_start[N_NODES] = val;  // total = N_EDGES
}

__global__ __launch_bounds__(256) void scan_final(const int* __restrict__ count,
                                                  const int* __restrict__ boff,
                                                  int* __restrict__ row_start,
                                                  int* __restrict__ cursor) {
  __shared__ int buf[256];
  const int t = threadIdx.x;
  const int i = blockIdx.x * 256 + t;
  const int v = (i < N_NODES) ? count[i] : 0;
  buf[t] = v;
  int val = v;
  for (int off = 1; off < 256; off <<= 1) {
    __syncthreads();
    const int tmp = (t >= off) ? buf[t - off] : 0;
    __syncthreads();
    val += tmp;
    buf[t] = val;
  }
  if (i < N_NODES) {
    const int ex = boff[blockIdx.x] + val - v;
    row_start[i] = ex;
    cursor[i] = ex;
  }
}

__global__ void scatter_kernel(const int* __restrict__ src,
                               const int* __restrict__ dst,
                               int* __restrict__ cursor,
                               int* __restrict__ csr_dst) {
  const int i = blockIdx.x * blockDim.x + threadIdx.x;
  if (i < N_EDGES) {
    const int s = src[i];
    const int pos = atomicAdd(&cursor[s], 1);
    csr_dst[pos] = dst[i];
  }
}

// ---------------- fused edge pass: one wave per src node, 2 edges/iter ----
__global__ __launch_bounds__(256) void gat_edge(const ushort* __restrict__ hb,
                                                const float* __restrict__ a,
                                                const int* __restrict__ row_start,
                                                const int* __restrict__ csr_dst,
                                                float* __restrict__ out) {
  const int wv = threadIdx.x >> 6;
  const int lane = threadIdx.x & 63;
  const int node = blockIdx.x * 4 + wv;
  if (node >= N_NODES) return;
  const int eoff = lane >> 5;
  const int l32 = lane & 31;
  const int head = l32 >> 2;
  const int c0 = l32 * 8;
  const float* ah = a + head * 160 + ((l32 & 3) * 8);

  float a1[8], a2[8], a3[8], a4v[8], a5[8];
  *(float4*)&a1[0] = *(const float4*)(ah + 0);   *(float4*)&a1[4] = *(const float4*)(ah + 4);
  *(float4*)&a2[0] = *(const float4*)(ah + 32);  *(float4*)&a2[4] = *(const float4*)(ah + 36);
  *(float4*)&a3[0] = *(const float4*)(ah + 64);  *(float4*)&a3[4] = *(const float4*)(ah + 68);
  *(float4*)&a4v[0] = *(const float4*)(ah + 96); *(float4*)&a4v[4] = *(const float4*)(ah + 100);
  *(float4*)&a5[0] = *(const float4*)(ah + 128); *(float4*)&a5[4] = *(const float4*)(ah + 132);

  float hs[8];
  unpack8(*(const uint4*)&hb[(size_t)node * 256 + c0], hs);
  float b[8];
  float cn = 0.f;
#pragma unroll
  for (int q = 0; q < 8; ++q) {
    b[q] = a2[q] + a3[q] + hs[q] * a5[q];
    cn += hs[q] * (a1[q] - a3[q]);
  }
  cn += __shfl_xor(cn, 1);
  cn += __shfl_xor(cn, 2);

  float m = -INFINITY, s = 0.f;
  float acc[8] = {0.f, 0.f, 0.f, 0.f, 0.f, 0.f, 0.f, 0.f};
  const int e0 = row_start[node], e1 = row_start[node + 1];
  const int cnt = e1 - e0;
  if (cnt > 0) {
    const int nit = (cnt + 1) >> 1;
    int idx = e0 + eoff;
    bool val = eoff < cnt;
    int j = csr_dst[val ? idx : e0];
    uint4 hv = *(const uint4*)&hb[(size_t)j * 256 + c0];
    for (int it = 0; it < nit; ++it) {
      const bool cv = val;
      const uint4 cur = hv;
      idx += 2;
      val = idx < e1;
      if (val) {
        j = csr_dst[idx];
        hv = *(const uint4*)&hb[(size_t)j * 256 + c0];
      }
      float hd[8];
      unpack8(cur, hd);
      float p = 0.f;
#pragma unroll
      for (int q = 0; q < 8; ++q)
        p += hd[q] * b[q] + fabsf(hd[q] - hs[q]) * a4v[q];
      p += __shfl_xor(p, 1);
      p += __shfl_xor(p, 2);
      if (cv) {
        const float lin = cn + p;
        const float alpha = lin > 0.f ? lin : 0.2f * lin;
        const float mn = fmaxf(m, alpha);
        const float r = __expf(m - mn);
        const float wgt = __expf(alpha - mn);
        s = s * r + wgt;
#pragma unroll
        for (int q = 0; q < 8; ++q) acc[q] = acc[q] * r + wgt * hd[q];
        m = mn;
      }
    }
  }
  const float mo = __shfl_xor(m, 32);
  const float so = __shfl_xor(s, 32);
  const float mn = fmaxf(m, mo);
  const float r1 = (m > -INFINITY) ? __expf(m - mn) : 0.f;
  const float r2 = (mo > -INFINITY) ? __expf(mo - mn) : 0.f;
  const float inv = 1.f / (s * r1 + so * r2 + 1e-16f);
  float o[8];
#pragma unroll
  for (int q = 0; q < 8; ++q) {
    const float ao = __shfl_xor(acc[q], 32);
    o[q] = (acc[q] * r1 + ao * r2) * inv;
  }
  if (eoff == 0) {
    *(float4*)&out[(size_t)node * 256 + c0] = make_float4(o[0], o[1], o[2], o[3]);
    *(float4*)&out[(size_t)node * 256 + c0 + 4] = make_float4(o[4], o[5], o[6], o[7]);
  }
}

extern "C" void kernel_launch(void* const* d_in, const int* in_sizes, int n_in,
                              void* d_out, int out_size, void* d_ws, size_t ws_size,
                              hipStream_t stream) {
  const float* x = (const float*)d_in[0];
  const float* W = (const float*)d_in[1];
  const float* a = (const float*)d_in[2];
  const int* src = (const int*)d_in[3];
  const int* dst = (const int*)d_in[4];
  float* out = (float*)d_out;

  char* ws = (char*)d_ws;
  ushort* hb = (ushort*)ws;
  size_t off = (size_t)N_NODES * 256 * 2;
  ushort* WT = (ushort*)(ws + off); off += 256 * 256 * 2;
  int* count = (int*)(ws + off);     off += 50048 * sizeof(int);
  int* row_start = (int*)(ws + off); off += 50048 * sizeof(int);
  int* cursor = (int*)(ws + off);    off += 50048 * sizeof(int);
  int* csr_dst = (int*)(ws + off);   off += (size_t)N_EDGES * sizeof(int);
  int* bsum = (int*)(ws + off);      off += 256 * sizeof(int);
  int* boff = (int*)(ws + off);      off += 256 * sizeof(int);

  ushort* xb = (ushort*)d_out;  // overwritten by gat_edge at the end

  hipMemsetAsync(count, 0, N_NODES * sizeof(int), stream);

  convert_x<<<12500, 256, 0, stream>>>(x, xb);
  convert_w<<<256, 256, 0, stream>>>(W, WT);

  hist_kernel<<<(N_EDGES + 255) / 256, 256, 0, stream>>>(src, count);
  block_sum<<<NB_SCAN, 256, 0, stream>>>(count, bsum);
  scan_bsums<<<1, 256, 0, stream>>>(bsum, boff, row_start);
  scan_final<<<NB_SCAN, 256, 0, stream>>>(count, boff, row_start, cursor);
  scatter_kernel<<<(N_EDGES + 255) / 256, 256, 0, stream>>>(src, dst, cursor, csr_dst);

  dim3 gemm_grid(391, 2);
  proj_gemm<<<gemm_grid, 256, 0, stream>>>(xb, WT, hb);

  gat_edge<<<12500, 256, 0, stream>>>(hb, a, row_start, csr_dst, out);
}

// Round 4
// 205.462 us; speedup vs baseline: 2.0117x; 1.0678x over previous
//
#include <hip/hip_runtime.h>
#include <hip/hip_bf16.h>
#include <cmath>

#define N_NODES 50000
#define N_EDGES 800000
#define NB_SCAN 196  // 196*256 = 50176 >= N_NODES
#define XBLK 12500
#define WBLK 256
#define HBLK 3125  // 3125*256 = 800000

typedef _Float16 h2 __attribute__((ext_vector_type(2)));
typedef _Float16 h8 __attribute__((ext_vector_type(8)));
typedef float f32x4 __attribute__((ext_vector_type(4)));

__device__ __forceinline__ float fdot2f(h2 a, h2 b, float c) {
#if __has_builtin(__builtin_amdgcn_fdot2)
  return __builtin_amdgcn_fdot2(a, b, c, false);
#else
  float d;
  asm("v_dot2_f32_f16 %0, %1, %2, %3" : "=v"(d) : "v"(a), "v"(b), "v"(c));
  return d;
#endif
}

__device__ __forceinline__ h2 habs2(h2 v) {
  union { h2 h; unsigned u; } t;
  t.h = v;
  t.u &= 0x7fff7fffu;
  return t.h;
}

// ---- fused prep: x->f16, WT[c][k]=f16(W[c/32][k][c%32]), edge histogram ----
__global__ __launch_bounds__(256) void prep(const float* __restrict__ x,
                                            const float* __restrict__ W,
                                            const int* __restrict__ src,
                                            ushort* __restrict__ xh,
                                            ushort* __restrict__ WTh,
                                            int* __restrict__ count) {
  const int b = blockIdx.x;
  if (b < XBLK) {
    const size_t i = (size_t)b * 256 + threadIdx.x;  // one float4 each
    const float4 v = *(const float4*)&x[i * 4];
    union { _Float16 h[4]; ushort4 u; } o;
    o.h[0] = (_Float16)v.x; o.h[1] = (_Float16)v.y;
    o.h[2] = (_Float16)v.z; o.h[3] = (_Float16)v.w;
    *(ushort4*)&xh[i * 4] = o.u;
  } else if (b < XBLK + WBLK) {
    const int c = b - XBLK, k = threadIdx.x;
    union { _Float16 h; ushort u; } o;
    o.h = (_Float16)W[((c >> 5) * 256 + k) * 32 + (c & 31)];
    WTh[c * 256 + k] = o.u;
  } else {
    const int i = (b - XBLK - WBLK) * 256 + threadIdx.x;
    if (i < N_EDGES) atomicAdd(&count[src[i]], 1);
  }
}

// ---- h = x @ W per head, f16 MFMA, packed f16 output ----
__global__ __launch_bounds__(256) void proj_gemm(const ushort* __restrict__ xh,
                                                 const ushort* __restrict__ WTh,
                                                 ushort* __restrict__ hh) {
  __shared__ ushort Xl[8][128][8];
  __shared__ ushort Wl[8][128][8];
  const int bm = blockIdx.x * 128;
  const int bch = blockIdx.y * 128;
  const int tid = threadIdx.x;
  const int w = tid >> 6, lane = tid & 63;
  const int wch = w >> 1, wnd = w & 1;
  const int l15 = lane & 15, l4 = lane >> 4;
  f32x4 acc[4][4] = {};
  for (int ks = 0; ks < 4; ++ks) {
    const int k0 = ks * 64;
    __syncthreads();
    for (int it = w; it < 32; it += 4) {
      const int kc = (it & 15) >> 1, half = it & 1;
      if (it < 16) {
        int row = bm + half * 64 + lane;
        row = row < N_NODES ? row : N_NODES - 1;
        const ushort* gp = xh + (size_t)row * 256 + k0 + kc * 8;
        __builtin_amdgcn_global_load_lds(
            (const __attribute__((address_space(1))) void*)gp,
            (__attribute__((address_space(3))) void*)&Xl[kc][half * 64][0],
            16, 0, 0);
      } else {
        const int crow = bch + half * 64 + lane;
        const ushort* gp = WTh + (size_t)crow * 256 + k0 + kc * 8;
        __builtin_amdgcn_global_load_lds(
            (const __attribute__((address_space(1))) void*)gp,
            (__attribute__((address_space(3))) void*)&Wl[kc][half * 64][0],
            16, 0, 0);
      }
    }
    __syncthreads();
#pragma unroll
    for (int t = 0; t < 2; ++t) {
      const int kc = t * 4 + l4;
      h8 bfr[4];
#pragma unroll
      for (int j = 0; j < 4; ++j)
        bfr[j] = *(const h8*)&Xl[kc][wnd * 64 + j * 16 + l15][0];
#pragma unroll
      for (int i = 0; i < 4; ++i) {
        const h8 af = *(const h8*)&Wl[kc][wch * 64 + i * 16 + l15][0];
#pragma unroll
        for (int j = 0; j < 4; ++j)
          acc[i][j] = __builtin_amdgcn_mfma_f32_16x16x32_f16(af, bfr[j],
                                                             acc[i][j], 0, 0, 0);
      }
    }
  }
#pragma unroll
  for (int i = 0; i < 4; ++i) {
#pragma unroll
    for (int j = 0; j < 4; ++j) {
      const int node = bm + wnd * 64 + j * 16 + l15;
      if (node < N_NODES) {
        const int ch = bch + wch * 64 + i * 16 + l4 * 4;
        union { _Float16 h[4]; ushort4 u; } o;
        o.h[0] = (_Float16)acc[i][j][0]; o.h[1] = (_Float16)acc[i][j][1];
        o.h[2] = (_Float16)acc[i][j][2]; o.h[3] = (_Float16)acc[i][j][3];
        *(ushort4*)&hh[(size_t)node * 256 + ch] = o.u;
      }
    }
  }
}

// ---------------- CSR build: hierarchical scan -> scatter ----------------
__global__ __launch_bounds__(256) void block_sum(const int* __restrict__ count,
                                                 int* __restrict__ bsum) {
  const int i = blockIdx.x * 256 + threadIdx.x;
  int v = (i < N_NODES) ? count[i] : 0;
#pragma unroll
  for (int off = 1; off < 64; off <<= 1) v += __shfl_xor(v, off);
  __shared__ int wsum[4];
  if ((threadIdx.x & 63) == 0) wsum[threadIdx.x >> 6] = v;
  __syncthreads();
  if (threadIdx.x == 0) bsum[blockIdx.x] = wsum[0] + wsum[1] + wsum[2] + wsum[3];
}

__global__ __launch_bounds__(256) void scan_bsums(const int* __restrict__ bsum,
                                                  int* __restrict__ boff,
                                                  int* __restrict__ row_start) {
  __shared__ int buf[256];
  const int t = threadIdx.x;
  const int v = (t < NB_SCAN) ? bsum[t] : 0;
  buf[t] = v;
  int val = v;
  for (int off = 1; off < 256; off <<= 1) {
    __syncthreads();
    const int tmp = (t >= off) ? buf[t - off] : 0;
    __syncthreads();
    val += tmp;
    buf[t] = val;
  }
  if (t < NB_SCAN) boff[t] = val - v;
  if (t == 255) row_start[N_NODES] = val;
}

__global__ __launch_bounds__(256) void scan_final(const int* __restrict__ count,
                                                  const int* __restrict__ boff,
                                                  int* __restrict__ row_start,
                                                  int* __restrict__ cursor) {
  __shared__ int buf[256];
  const int t = threadIdx.x;
  const int i = blockIdx.x * 256 + t;
  const int v = (i < N_NODES) ? count[i] : 0;
  buf[t] = v;
  int val = v;
  for (int off = 1; off < 256; off <<= 1) {
    __syncthreads();
    const int tmp = (t >= off) ? buf[t - off] : 0;
    __syncthreads();
    val += tmp;
    buf[t] = val;
  }
  if (i < N_NODES) {
    const int ex = boff[blockIdx.x] + val - v;
    row_start[i] = ex;
    cursor[i] = ex;
  }
}

__global__ void scatter_kernel(const int* __restrict__ src,
                               const int* __restrict__ dst,
                               int* __restrict__ cursor,
                               int* __restrict__ csr_dst) {
  const int i = blockIdx.x * blockDim.x + threadIdx.x;
  if (i < N_EDGES) {
    const int s = src[i];
    const int pos = atomicAdd(&cursor[s], 1);
    csr_dst[pos] = dst[i];
  }
}

// ---------------- fused edge pass: one wave per src node, 2 edges/iter ----
// lanes 0-31 even edges, 32-63 odd edges; 8 channels/lane, packed f16 math:
// v_dot2_f32_f16 for logits, v_pk_fma_f16 for the accumulator.
__global__ __launch_bounds__(256) void gat_edge(const ushort* __restrict__ hh,
                                                const float* __restrict__ a,
                                                const int* __restrict__ row_start,
                                                const int* __restrict__ csr_dst,
                                                float* __restrict__ out) {
  const int wv = threadIdx.x >> 6;
  const int lane = threadIdx.x & 63;
  const int node = blockIdx.x * 4 + wv;
  if (node >= N_NODES) return;
  const int eoff = lane >> 5;
  const int l32 = lane & 31;
  const int head = l32 >> 2;
  const int c0 = l32 * 8;
  const float* ah = a + head * 160 + ((l32 & 3) * 8);

  float a1[8], a2[8], a3[8], a4v[8], a5[8];
  *(float4*)&a1[0] = *(const float4*)(ah + 0);   *(float4*)&a1[4] = *(const float4*)(ah + 4);
  *(float4*)&a2[0] = *(const float4*)(ah + 32);  *(float4*)&a2[4] = *(const float4*)(ah + 36);
  *(float4*)&a3[0] = *(const float4*)(ah + 64);  *(float4*)&a3[4] = *(const float4*)(ah + 68);
  *(float4*)&a4v[0] = *(const float4*)(ah + 96); *(float4*)&a4v[4] = *(const float4*)(ah + 100);
  *(float4*)&a5[0] = *(const float4*)(ah + 128); *(float4*)&a5[4] = *(const float4*)(ah + 132);

  union HU { uint4 u4; h2 h[4]; };
  HU hsu;
  hsu.u4 = *(const uint4*)&hh[(size_t)node * 256 + c0];
  h2 hs2[4], b2[4], a42[4];
  float cn = 0.f;
#pragma unroll
  for (int q = 0; q < 4; ++q) {
    hs2[q] = hsu.h[q];
    const float h0 = (float)hs2[q][0], h1 = (float)hs2[q][1];
    const float b0 = a2[2 * q] + a3[2 * q] + h0 * a5[2 * q];
    const float b1 = a2[2 * q + 1] + a3[2 * q + 1] + h1 * a5[2 * q + 1];
    b2[q] = h2{(_Float16)b0, (_Float16)b1};
    a42[q] = h2{(_Float16)a4v[2 * q], (_Float16)a4v[2 * q + 1]};
    cn += h0 * (a1[2 * q] - a3[2 * q]) + h1 * (a1[2 * q + 1] - a3[2 * q + 1]);
  }
  cn += __shfl_xor(cn, 1);
  cn += __shfl_xor(cn, 2);

  float m = -INFINITY, s = 0.f;
  h2 acc2[4] = {};
  const int e0 = row_start[node], e1 = row_start[node + 1];
  const int cnt = e1 - e0;
  if (cnt > 0) {
    const int nit = (cnt + 1) >> 1;
    int idx = e0 + eoff;
    bool val = eoff < cnt;
    int j = csr_dst[val ? idx : e0];
    uint4 hv = *(const uint4*)&hh[(size_t)j * 256 + c0];
    for (int it = 0; it < nit; ++it) {
      const bool cv = val;
      HU cur;
      cur.u4 = hv;
      idx += 2;
      val = idx < e1;
      if (val) {  // prefetch next pair's gather under this pair's compute
        j = csr_dst[idx];
        hv = *(const uint4*)&hh[(size_t)j * 256 + c0];
      }
      float p = 0.f;
#pragma unroll
      for (int q = 0; q < 4; ++q) {
        p = fdot2f(cur.h[q], b2[q], p);
        h2 d = cur.h[q] - hs2[q];
        p = fdot2f(habs2(d), a42[q], p);
      }
      p += __shfl_xor(p, 1);
      p += __shfl_xor(p, 2);
      if (cv) {
        const float lin = cn + p;
        const float alpha = lin > 0.f ? lin : 0.2f * lin;
        const float mn = fmaxf(m, alpha);
        const float r = __expf(m - mn);
        const float wgt = __expf(alpha - mn);
        s = s * r + wgt;
        const h2 r2 = h2{(_Float16)r, (_Float16)r};
        const h2 w2 = h2{(_Float16)wgt, (_Float16)wgt};
#pragma unroll
        for (int q = 0; q < 4; ++q) acc2[q] = acc2[q] * r2 + w2 * cur.h[q];
        m = mn;
      }
    }
  }
  // merge the two half-wave softmax streams
  const float mo = __shfl_xor(m, 32);
  const float so = __shfl_xor(s, 32);
  const float mn = fmaxf(m, mo);
  const float r1 = (m > -INFINITY) ? __expf(m - mn) : 0.f;
  const float r2 = (mo > -INFINITY) ? __expf(mo - mn) : 0.f;
  const float inv = 1.f / (s * r1 + so * r2 + 1e-16f);
  float o[8];
#pragma unroll
  for (int q = 0; q < 4; ++q) {
    o[2 * q] = (float)acc2[q][0];
    o[2 * q + 1] = (float)acc2[q][1];
  }
#pragma unroll
  for (int q = 0; q < 8; ++q) {
    const float ao = __shfl_xor(o[q], 32);
    o[q] = (o[q] * r1 + ao * r2) * inv;
  }
  if (eoff == 0) {
    *(float4*)&out[(size_t)node * 256 + c0] = make_float4(o[0], o[1], o[2], o[3]);
    *(float4*)&out[(size_t)node * 256 + c0 + 4] = make_float4(o[4], o[5], o[6], o[7]);
  }
}

extern "C" void kernel_launch(void* const* d_in, const int* in_sizes, int n_in,
                              void* d_out, int out_size, void* d_ws, size_t ws_size,
                              hipStream_t stream) {
  const float* x = (const float*)d_in[0];
  const float* W = (const float*)d_in[1];
  const float* a = (const float*)d_in[2];
  const int* src = (const int*)d_in[3];
  const int* dst = (const int*)d_in[4];
  float* out = (float*)d_out;

  char* ws = (char*)d_ws;
  ushort* hh = (ushort*)ws;
  size_t off = (size_t)N_NODES * 256 * 2;
  ushort* WTh = (ushort*)(ws + off); off += 256 * 256 * 2;
  int* count = (int*)(ws + off);     off += 50048 * sizeof(int);
  int* row_start = (int*)(ws + off); off += 50048 * sizeof(int);
  int* cursor = (int*)(ws + off);    off += 50048 * sizeof(int);
  int* csr_dst = (int*)(ws + off);   off += (size_t)N_EDGES * sizeof(int);
  int* bsum = (int*)(ws + off);      off += 256 * sizeof(int);
  int* boff = (int*)(ws + off);      off += 256 * sizeof(int);

  ushort* xh = (ushort*)d_out;  // overwritten by gat_edge at the end

  hipMemsetAsync(count, 0, N_NODES * sizeof(int), stream);

  prep<<<XBLK + WBLK + HBLK, 256, 0, stream>>>(x, W, src, xh, WTh, count);
  block_sum<<<NB_SCAN, 256, 0, stream>>>(count, bsum);
  scan_bsums<<<1, 256, 0, stream>>>(bsum, boff, row_start);
  scan_final<<<NB_SCAN, 256, 0, stream>>>(count, boff, row_start, cursor);
  scatter_kernel<<<HBLK, 256, 0, stream>>>(src, dst, cursor, csr_dst);

  dim3 gemm_grid(391, 2);
  proj_gemm<<<gemm_grid, 256, 0, stream>>>(xh, WTh, hh);

  gat_edge<<<12500, 256, 0, stream>>>(hh, a, row_start, csr_dst, out);
}